// Round 4
// baseline (472.342 us; speedup 1.0000x reference)
//
#include <hip/hip_runtime.h>
#include <hip/hip_bf16.h>
#include <stdint.h>

typedef __attribute__((ext_vector_type(8))) short short8;   // 8 bf16 (4 VGPRs)
typedef __attribute__((ext_vector_type(4))) float f32x4;

#define IN_DIM 128
#define OUT_DIM 128
#define NROWS 524288
#define TILES_PER_BLOCK 4
#define NBLOCKS (NROWS / (64 * TILES_PER_BLOCK))   // 2048

__device__ __forceinline__ ushort f2bf(float f) {
    __hip_bfloat16 h = __float2bfloat16(f);
    union { __hip_bfloat16 h; ushort u; } cv;
    cv.h = h;
    return cv.u;
}

// y[m][n] = sum_k x[m][k] * W[n][k] + b[n]
// Operand-swapped: A = W (rows = 16 outputs n), B = x (cols = 16 batch rows m).
// D[n][m]: lane l -> m = l&15 (one out row per lane), n = (l>>4)*4 + reg
// => each lane stores f32x4 of 4 CONSECUTIVE out columns: fully vectorized stores.
__global__ __launch_bounds__(256) void linear_kernel(
    const float* __restrict__ x,
    const float* __restrict__ wgt,
    const float* __restrict__ bias,
    float* __restrict__ out)
{
    // W in MFMA A-fragment order: entry g=(kk*8+nt)*64+lane holds 8 bf16 (16B)
    // (A and B fragments share the same lane->(idx,k) map: idx=l&15, k=(l>>4)*8+j)
    __shared__ short8 wlds[2048];   // 32 KiB

    const int t = threadIdx.x;

    // ---- stage W f32 -> bf16 fragments in LDS (W is L2-resident: 64 KB) ----
    #pragma unroll
    for (int i = 0; i < 8; ++i) {
        int g  = i * 256 + t;
        int kk = g >> 9, nt = (g >> 6) & 7, ln = g & 63;
        int row   = nt * 16 + (ln & 15);          // W output row n
        int kbase = kk * 32 + ((ln >> 4) << 3);
        const float* src = wgt + row * IN_DIM + kbase;
        f32x4 lo = *reinterpret_cast<const f32x4*>(src);
        f32x4 hi = *reinterpret_cast<const f32x4*>(src + 4);
        short8 v;
        v[0] = (short)f2bf(lo[0]); v[1] = (short)f2bf(lo[1]);
        v[2] = (short)f2bf(lo[2]); v[3] = (short)f2bf(lo[3]);
        v[4] = (short)f2bf(hi[0]); v[5] = (short)f2bf(hi[1]);
        v[6] = (short)f2bf(hi[2]); v[7] = (short)f2bf(hi[3]);
        wlds[g] = v;
    }

    const int l  = t & 63;
    const int wv = t >> 6;      // wave id 0..3
    const int r  = l & 15;      // lane's batch row within the 16-row strip
    const int q  = l >> 4;      // quarter: n = q*4 + reg within each 16-block

    // bias fragment: lane needs bias[nt*16 + q*4 .. +4] (vector, uniform over r)
    f32x4 bfrag[8];
    #pragma unroll
    for (int nt = 0; nt < 8; ++nt)
        bfrag[nt] = *reinterpret_cast<const f32x4*>(bias + nt * 16 + (q << 2));

    __syncthreads();

    const long tile0 = (long)blockIdx.x * TILES_PER_BLOCK;
    for (int tt = 0; tt < TILES_PER_BLOCK; ++tt) {
        const long m0 = (tile0 + tt) * 64 + wv * 16;   // this wave's 16-row strip
        const float* xp = x + (m0 + r) * IN_DIM + (q << 3);

        // B fragments (x): lane l holds row m0+(l&15), k = (l>>4)*8 + j
        short8 a[4];
        #pragma unroll
        for (int kk = 0; kk < 4; ++kk) {
            f32x4 lo = *reinterpret_cast<const f32x4*>(xp + kk * 32);
            f32x4 hi = *reinterpret_cast<const f32x4*>(xp + kk * 32 + 4);
            short8 v;
            v[0] = (short)f2bf(lo[0]); v[1] = (short)f2bf(lo[1]);
            v[2] = (short)f2bf(lo[2]); v[3] = (short)f2bf(lo[3]);
            v[4] = (short)f2bf(hi[0]); v[5] = (short)f2bf(hi[1]);
            v[6] = (short)f2bf(hi[2]); v[7] = (short)f2bf(hi[3]);
            a[kk] = v;
        }

        f32x4 acc[8];
        #pragma unroll
        for (int nt = 0; nt < 8; ++nt) acc[nt] = (f32x4)(0.0f);

        #pragma unroll
        for (int kk = 0; kk < 4; ++kk) {
            #pragma unroll
            for (int nt = 0; nt < 8; ++nt) {
                acc[nt] = __builtin_amdgcn_mfma_f32_16x16x32_bf16(
                    wlds[(kk * 8 + nt) * 64 + l], a[kk], acc[nt], 0, 0, 0);
            }
        }

        // D[n][m]: lane l owns out row m0+r, cols nt*16 + q*4 .. +4 -> f32x4 stores
        float* op = out + (m0 + r) * OUT_DIM + (q << 2);
        #pragma unroll
        for (int nt = 0; nt < 8; ++nt) {
            f32x4 v = acc[nt] + bfrag[nt];
            __builtin_nontemporal_store(v, reinterpret_cast<f32x4*>(op + nt * 16));
        }
    }
}

extern "C" void kernel_launch(void* const* d_in, const int* in_sizes, int n_in,
                              void* d_out, int out_size, void* d_ws, size_t ws_size,
                              hipStream_t stream) {
    const float* x  = (const float*)d_in[0];
    const float* w  = (const float*)d_in[1];
    const float* b  = (const float*)d_in[2];
    float* out      = (float*)d_out;
    linear_kernel<<<dim3(NBLOCKS), dim3(256), 0, stream>>>(x, w, b, out);
}

// Round 5
// 460.419 us; speedup vs baseline: 1.0259x; 1.0259x over previous
//
#include <hip/hip_runtime.h>
#include <hip/hip_bf16.h>
#include <stdint.h>

typedef __attribute__((ext_vector_type(8))) short short8;   // 8 bf16 (4 VGPRs)
typedef __attribute__((ext_vector_type(4))) float f32x4;

#define IN_DIM 128
#define OUT_DIM 128
#define NROWS 524288
#define THREADS 512
#define ROWS_PER_BLOCK 128                    // 8 waves x 16 rows
#define NBLOCKS (NROWS / ROWS_PER_BLOCK)      // 4096

__device__ __forceinline__ ushort f2bf(float f) {
    __hip_bfloat16 h = __float2bfloat16(f);
    union { __hip_bfloat16 h; ushort u; } cv;
    cv.h = h;
    return cv.u;
}

// y[m][n] = sum_k x[m][k] * W[n][k] + b[n]
// Operand-swapped MFMA: A = W (from LDS), B = x. D[n][m]: lane l -> out row
// m = m0 + (l&15), cols nt*16 + (l>>4)*4 .. +4  => f32x4 stores.
// 512-thr blocks: 4 blocks/CU (waves-capped) -> 32 waves/CU, 128 KiB LDS/CU.
__global__ __launch_bounds__(THREADS, 8) void linear_kernel(
    const float* __restrict__ x,
    const float* __restrict__ wgt,
    const float* __restrict__ bias,
    float* __restrict__ out)
{
    // W in MFMA A-fragment order: entry g=(kk*8+nt)*64+lane holds 8 bf16 (16B)
    __shared__ short8 wlds[2048];   // 32 KiB

    const int t  = threadIdx.x;
    const int l  = t & 63;
    const int wv = t >> 6;      // wave id 0..7
    const int r  = l & 15;      // lane's batch row within the 16-row strip
    const int q  = l >> 4;      // quarter: out col = nt*16 + q*4 + reg

    const long m0 = (long)blockIdx.x * ROWS_PER_BLOCK + wv * 16;
    const float* xp = x + (m0 + r) * IN_DIM + (q << 3);

    // ---- issue x loads FIRST: 8x16B per lane in flight across W staging ----
    f32x4 xv[8];
    #pragma unroll
    for (int kk = 0; kk < 4; ++kk) {
        xv[2 * kk]     = *reinterpret_cast<const f32x4*>(xp + kk * 32);
        xv[2 * kk + 1] = *reinterpret_cast<const f32x4*>(xp + kk * 32 + 4);
    }

    // ---- stage W f32 -> bf16 fragments in LDS (W is L2-resident: 64 KB) ----
    #pragma unroll
    for (int i = 0; i < 4; ++i) {
        int g  = i * THREADS + t;
        int kk = g >> 9, nt = (g >> 6) & 7, ln = g & 63;
        int row   = nt * 16 + (ln & 15);          // W output row n
        int kbase = kk * 32 + ((ln >> 4) << 3);
        const float* src = wgt + row * IN_DIM + kbase;
        f32x4 lo = *reinterpret_cast<const f32x4*>(src);
        f32x4 hi = *reinterpret_cast<const f32x4*>(src + 4);
        short8 v;
        v[0] = (short)f2bf(lo[0]); v[1] = (short)f2bf(lo[1]);
        v[2] = (short)f2bf(lo[2]); v[3] = (short)f2bf(lo[3]);
        v[4] = (short)f2bf(hi[0]); v[5] = (short)f2bf(hi[1]);
        v[6] = (short)f2bf(hi[2]); v[7] = (short)f2bf(hi[3]);
        wlds[g] = v;
    }

    __syncthreads();

    // ---- cvt x to bf16 B-fragments ----
    short8 a[4];
    #pragma unroll
    for (int kk = 0; kk < 4; ++kk) {
        f32x4 lo = xv[2 * kk], hi = xv[2 * kk + 1];
        short8 v;
        v[0] = (short)f2bf(lo[0]); v[1] = (short)f2bf(lo[1]);
        v[2] = (short)f2bf(lo[2]); v[3] = (short)f2bf(lo[3]);
        v[4] = (short)f2bf(hi[0]); v[5] = (short)f2bf(hi[1]);
        v[6] = (short)f2bf(hi[2]); v[7] = (short)f2bf(hi[3]);
        a[kk] = v;
    }

    f32x4 acc[8];
    #pragma unroll
    for (int nt = 0; nt < 8; ++nt) acc[nt] = (f32x4)(0.0f);

    #pragma unroll
    for (int kk = 0; kk < 4; ++kk) {
        #pragma unroll
        for (int nt = 0; nt < 8; ++nt) {
            acc[nt] = __builtin_amdgcn_mfma_f32_16x16x32_bf16(
                wlds[(kk * 8 + nt) * 64 + l], a[kk], acc[nt], 0, 0, 0);
        }
    }

    // ---- epilogue: bias (L2-resident) + plain vectorized stores ----
    float* op = out + (m0 + r) * OUT_DIM + (q << 2);
    #pragma unroll
    for (int nt = 0; nt < 8; ++nt) {
        f32x4 b4 = *reinterpret_cast<const f32x4*>(bias + nt * 16 + (q << 2));
        f32x4 v  = acc[nt] + b4;
        *reinterpret_cast<f32x4*>(op + nt * 16) = v;
    }
}

extern "C" void kernel_launch(void* const* d_in, const int* in_sizes, int n_in,
                              void* d_out, int out_size, void* d_ws, size_t ws_size,
                              hipStream_t stream) {
    const float* x  = (const float*)d_in[0];
    const float* w  = (const float*)d_in[1];
    const float* b  = (const float*)d_in[2];
    float* out      = (float*)d_out;
    linear_kernel<<<dim3(NBLOCKS), dim3(THREADS), 0, stream>>>(x, w, b, out);
}